// Round 1
// baseline (291.039 us; speedup 1.0000x reference)
//
#include <hip/hip_runtime.h>
#include <hip/hip_bf16.h>

// Problem constants
#define NN     3072
#define NWORDS 48          // 3072/64 bit-words per row
#define INCH   128
#define HID    256
#define NHEADS 12
#define PLANE  9437184LL   // 3072*3072

typedef __attribute__((ext_vector_type(8))) short     s16x8;
typedef __attribute__((ext_vector_type(4))) float     f32x4;
typedef __attribute__((ext_vector_type(8))) unsigned short u16x8;

__device__ inline unsigned short bf16_rne(float f) {
    unsigned int u = __float_as_uint(f);
    u += 0x7FFFu + ((u >> 16) & 1u);
    return (unsigned short)(u >> 16);
}

// ---------------------------------------------------------------------------
// K1: stream attn (453 MB), agg = b + sum_c w[c]*attn[c], threshold -> bitmask
// grid 36864 x 256.  Bit (s,t) at mask[s*48 + t/64], bit t%64. Diagonal forced 1.
// ---------------------------------------------------------------------------
__global__ __launch_bounds__(256) void k_adj(const float* __restrict__ attn,
                                             const float* __restrict__ agg_w,
                                             const float* __restrict__ agg_b,
                                             unsigned long long* __restrict__ mask) {
    const int t = (blockIdx.x % 12) * 256 + threadIdx.x;
    const int s = blockIdx.x / 12;
    const long long idx = (long long)s * NN + t;
    float w[12];
#pragma unroll
    for (int c = 0; c < NHEADS; ++c) w[c] = agg_w[c];
    float acc = agg_b[0];
#pragma unroll
    for (int c = 0; c < NHEADS; ++c)
        acc = fmaf(w[c], attn[(long long)c * PLANE + idx], acc);
    bool pred = (acc > 0.0f) || (s == t);
    unsigned long long b = __ballot(pred);
    if ((threadIdx.x & 63) == 0)
        mask[s * NWORDS + (t >> 6)] = b;
}

// ---------------------------------------------------------------------------
// K2: deg partials. deg[t] = sum_s bit[s][t].  grid 72 x 256, 6 s-chunks of 512.
// degP[c*3072 + t]
// ---------------------------------------------------------------------------
__global__ __launch_bounds__(256) void k_degp(const unsigned long long* __restrict__ mask,
                                              int* __restrict__ degP) {
    int gid = blockIdx.x * 256 + threadIdx.x;     // 18432
    int t = gid % NN, c = gid / NN;
    int wv = t >> 6, bpos = t & 63;
    int cnt = 0;
    for (int s = c * 512; s < c * 512 + 512; ++s)
        cnt += (int)((mask[s * NWORDS + wv] >> bpos) & 1ULL);
    degP[gid] = cnt;
}

// K3: dinv = rsqrt(deg).  grid 12 x 256.
__global__ __launch_bounds__(256) void k_dinv(const int* __restrict__ degP,
                                              float* __restrict__ dinv) {
    int t = blockIdx.x * 256 + threadIdx.x;
    int d = 0;
#pragma unroll
    for (int c = 0; c < 6; ++c) d += degP[c * NN + t];
    dinv[t] = rsqrtf((float)d);   // deg >= 1 always (self loop)
}

// ---------------------------------------------------------------------------
// K4: w2sum partials: w2p[c][s] = sum over t-chunk of dinv[t]*bit[s][t]
// grid 72 x 256 (6 word-chunks of 8 words = 512 t each)
// ---------------------------------------------------------------------------
__global__ __launch_bounds__(256) void k_w2p(const unsigned long long* __restrict__ mask,
                                             const float* __restrict__ dinv,
                                             float* __restrict__ w2p) {
    int gid = blockIdx.x * 256 + threadIdx.x;
    int s = gid % NN, c = gid / NN;
    float acc = 0.0f;
    for (int w = c * 8; w < c * 8 + 8; ++w) {
        unsigned long long m = mask[s * NWORDS + w];
        int tbase = w * 64;
#pragma unroll 8
        for (int b = 0; b < 64; ++b)
            acc += ((m >> b) & 1ULL) ? dinv[tbase + b] : 0.0f;
    }
    w2p[c * NN + s] = acc;
}

// K5: w2sum[s] = dinv[s] * sum_c w2p[c][s].  grid 12 x 256.
__global__ __launch_bounds__(256) void k_w2r(const float* __restrict__ w2p,
                                             const float* __restrict__ dinv,
                                             float* __restrict__ w2sum) {
    int s = blockIdx.x * 256 + threadIdx.x;
    float acc = 0.0f;
#pragma unroll
    for (int c = 0; c < 6; ++c) acc += w2p[c * NN + s];
    w2sum[s] = dinv[s] * acc;
}

// ---------------------------------------------------------------------------
// K6: expand bits -> ATn[t][s] = bf16(dinv[t]*dinv[s]*bit[s][t])   (18.9 MB)
// thread <-> (t, 64-s chunk); grid 576 x 256
// ---------------------------------------------------------------------------
__global__ __launch_bounds__(256) void k_exp(const unsigned long long* __restrict__ mask,
                                             const float* __restrict__ dinv,
                                             unsigned short* __restrict__ ATn) {
    int gid = blockIdx.x * 256 + threadIdx.x;   // 147456
    int t = gid / NWORDS, ch = gid % NWORDS;
    float dt = dinv[t];
    int bpos = t & 63, wcol = t >> 6;
#pragma unroll 2
    for (int g = 0; g < 8; ++g) {
        u16x8 v;
#pragma unroll
        for (int j = 0; j < 8; ++j) {
            int s = ch * 64 + g * 8 + j;
            unsigned long long m = mask[s * NWORDS + wcol];
            float val = ((m >> bpos) & 1ULL) ? dt * dinv[s] : 0.0f;
            v[j] = bf16_rne(val);
        }
        *(u16x8*)(ATn + (long long)t * NN + ch * 64 + g * 8) = v;
    }
}

// ---------------------------------------------------------------------------
// K7: y1t[d][s] = bf16( (x @ W1)[s][d] )  transposed store for MFMA B-operand.
// block = 8 s-rows, 256 threads (thread = d). grid 384.
// ---------------------------------------------------------------------------
__global__ __launch_bounds__(256) void k_y1(const float* __restrict__ x,
                                            const float* __restrict__ W1,
                                            unsigned short* __restrict__ y1t) {
    __shared__ float xs[8][INCH];
    int s0 = blockIdx.x * 8;
    for (int i = threadIdx.x; i < 8 * INCH; i += 256)
        xs[i >> 7][i & 127] = x[s0 * INCH + i];
    __syncthreads();
    int d = threadIdx.x;
    float acc[8] = {0, 0, 0, 0, 0, 0, 0, 0};
    for (int k = 0; k < INCH; ++k) {
        float w = W1[k * HID + d];
#pragma unroll
        for (int r = 0; r < 8; ++r) acc[r] = fmaf(xs[r][k], w, acc[r]);
    }
    u16x8 v;
#pragma unroll
    for (int r = 0; r < 8; ++r) v[r] = bf16_rne(acc[r]);
    *(u16x8*)(y1t + (long long)d * NN + s0) = v;
}

// ---------------------------------------------------------------------------
// K8: prop1 MFMA GEMM: h1r[t][d] = relu( sum_s ATn[t][s]*y1[s][d] + b1[d] )
// M=3072(t) N=256(d) K=3072(s). Block 256thr/4 waves, BM=64, BN=64. grid (48,4).
// mfma_f32_16x16x32_bf16: A lane(l): row=l&15, k=(l>>4)*8+j (K-contig 16B)
//                         B lane(l): col=l&15, k=(l>>4)*8+j (K-contig 16B)
//                         D lane(l): col=l&15, row=(l>>4)*4+reg
// ---------------------------------------------------------------------------
__global__ __launch_bounds__(256) void k_prop1(const unsigned short* __restrict__ ATn,
                                               const unsigned short* __restrict__ y1t,
                                               const float* __restrict__ b1,
                                               float* __restrict__ h1r) {
    int w = threadIdx.x >> 6, l = threadIdx.x & 63;
    int lr = l & 15, lg = l >> 4;
    int t0 = blockIdx.x * 64 + w * 16;
    int d0 = blockIdx.y * 64;

    const unsigned short* Arow = ATn + (long long)(t0 + lr) * NN + lg * 8;
    const unsigned short* B0 = y1t + (long long)(d0 + 0 * 16 + lr) * NN + lg * 8;
    const unsigned short* B1 = y1t + (long long)(d0 + 1 * 16 + lr) * NN + lg * 8;
    const unsigned short* B2 = y1t + (long long)(d0 + 2 * 16 + lr) * NN + lg * 8;
    const unsigned short* B3 = y1t + (long long)(d0 + 3 * 16 + lr) * NN + lg * 8;

    f32x4 acc0 = {0, 0, 0, 0}, acc1 = {0, 0, 0, 0}, acc2 = {0, 0, 0, 0}, acc3 = {0, 0, 0, 0};

#pragma unroll 4
    for (int s = 0; s < NN; s += 32) {
        s16x8 a  = *(const s16x8*)(const void*)(Arow + s);
        s16x8 b0 = *(const s16x8*)(const void*)(B0 + s);
        s16x8 b1f = *(const s16x8*)(const void*)(B1 + s);
        s16x8 b2f = *(const s16x8*)(const void*)(B2 + s);
        s16x8 b3f = *(const s16x8*)(const void*)(B3 + s);
        acc0 = __builtin_amdgcn_mfma_f32_16x16x32_bf16(a, b0, acc0, 0, 0, 0);
        acc1 = __builtin_amdgcn_mfma_f32_16x16x32_bf16(a, b1f, acc1, 0, 0, 0);
        acc2 = __builtin_amdgcn_mfma_f32_16x16x32_bf16(a, b2f, acc2, 0, 0, 0);
        acc3 = __builtin_amdgcn_mfma_f32_16x16x32_bf16(a, b3f, acc3, 0, 0, 0);
    }

    int trow = t0 + lg * 4;
    f32x4 accs[4] = {acc0, acc1, acc2, acc3};
#pragma unroll
    for (int dt = 0; dt < 4; ++dt) {
        int d = d0 + dt * 16 + lr;
        float bb = b1[d];
#pragma unroll
        for (int r = 0; r < 4; ++r) {
            float v = accs[dt][r] + bb;
            h1r[(long long)(trow + r) * HID + d] = fmaxf(v, 0.0f);
        }
    }
}

// ---------------------------------------------------------------------------
// K9: v partials: vp[c][d] = sum_{s in chunk} w2sum[s]*h1r[s][d].  grid 12 x 256.
// ---------------------------------------------------------------------------
__global__ __launch_bounds__(256) void k_v(const float* __restrict__ w2sum,
                                           const float* __restrict__ h1r,
                                           float* __restrict__ vp) {
    int c = blockIdx.x, d = threadIdx.x;
    float acc = 0.0f;
    for (int s = c * 256; s < c * 256 + 256; ++s)
        acc = fmaf(w2sum[s], h1r[(long long)s * HID + d], acc);
    vp[c * HID + d] = acc;
}

// ---------------------------------------------------------------------------
// K10: head. g = b2 + (v@W2)/3072 ; z=relu(g@l1W+l1b); LN; out = z@l2W+l2b.
// single block of 256 threads.
// ---------------------------------------------------------------------------
__global__ __launch_bounds__(256) void k_head(const float* __restrict__ vp,
                                              const float* __restrict__ W2,
                                              const float* __restrict__ b2,
                                              const float* __restrict__ l1W,
                                              const float* __restrict__ l1b,
                                              const float* __restrict__ lng,
                                              const float* __restrict__ lnb,
                                              const float* __restrict__ l2W,
                                              const float* __restrict__ l2b,
                                              float* __restrict__ out) {
    __shared__ float vs[HID], gs[HID], zs[HID], red[4];
    int d = threadIdx.x;
    float v = 0.0f;
#pragma unroll
    for (int c = 0; c < 12; ++c) v += vp[c * HID + d];
    vs[d] = v;
    __syncthreads();
    float a = 0.0f;
    for (int k = 0; k < HID; ++k) a = fmaf(vs[k], W2[k * HID + d], a);
    gs[d] = b2[d] + a * (1.0f / 3072.0f);
    __syncthreads();
    float z1 = l1b[d];
    for (int k = 0; k < HID; ++k) z1 = fmaf(gs[k], l1W[k * HID + d], z1);
    z1 = fmaxf(z1, 0.0f);
    // mean
    float sum = z1;
    for (int o = 1; o < 64; o <<= 1) sum += __shfl_xor(sum, o);
    if ((d & 63) == 0) red[d >> 6] = sum;
    __syncthreads();
    float mu = (red[0] + red[1] + red[2] + red[3]) * (1.0f / 256.0f);
    __syncthreads();
    float diff = z1 - mu, sq = diff * diff;
    for (int o = 1; o < 64; o <<= 1) sq += __shfl_xor(sq, o);
    if ((d & 63) == 0) red[d >> 6] = sq;
    __syncthreads();
    float var = (red[0] + red[1] + red[2] + red[3]) * (1.0f / 256.0f);
    float zn = diff * rsqrtf(var + 1e-5f) * lng[d] + lnb[d];
    zs[d] = zn;
    __syncthreads();
    if (d < 32) {
        float o = l2b[d];
        for (int k = 0; k < HID; ++k) o = fmaf(zs[k], l2W[k * 32 + d], o);
        out[d] = o;
    }
}

// ---------------------------------------------------------------------------
extern "C" void kernel_launch(void* const* d_in, const int* in_sizes, int n_in,
                              void* d_out, int out_size, void* d_ws, size_t ws_size,
                              hipStream_t stream) {
    const float* x     = (const float*)d_in[0];
    const float* attn  = (const float*)d_in[1];
    const float* agg_w = (const float*)d_in[4];
    const float* agg_b = (const float*)d_in[5];
    const float* W1    = (const float*)d_in[6];
    const float* b1    = (const float*)d_in[7];
    const float* W2    = (const float*)d_in[8];
    const float* b2    = (const float*)d_in[9];
    const float* l1W   = (const float*)d_in[10];
    const float* l1b   = (const float*)d_in[11];
    const float* lng   = (const float*)d_in[12];
    const float* lnb   = (const float*)d_in[13];
    const float* l2W   = (const float*)d_in[14];
    const float* l2b   = (const float*)d_in[15];
    float* out = (float*)d_out;

    char* ws = (char*)d_ws;
    size_t off = 0;
    auto alloc = [&](size_t bytes) -> void* {
        off = (off + 255) & ~(size_t)255;
        void* p = ws + off;
        off += bytes;
        return p;
    };
    unsigned long long* mask = (unsigned long long*)alloc((size_t)NN * NWORDS * 8);
    int*            degP  = (int*)  alloc((size_t)6 * NN * 4);
    float*          dinv  = (float*)alloc((size_t)NN * 4);
    float*          w2p   = (float*)alloc((size_t)6 * NN * 4);
    float*          w2sum = (float*)alloc((size_t)NN * 4);
    unsigned short* ATn   = (unsigned short*)alloc((size_t)NN * NN * 2);
    unsigned short* y1t   = (unsigned short*)alloc((size_t)HID * NN * 2);
    float*          h1r   = (float*)alloc((size_t)NN * HID * 4);
    float*          vp    = (float*)alloc((size_t)12 * HID * 4);

    hipLaunchKernelGGL(k_adj,  dim3(36864), dim3(256), 0, stream, attn, agg_w, agg_b, mask);
    hipLaunchKernelGGL(k_degp, dim3(72),    dim3(256), 0, stream, mask, degP);
    hipLaunchKernelGGL(k_dinv, dim3(12),    dim3(256), 0, stream, degP, dinv);
    hipLaunchKernelGGL(k_w2p,  dim3(72),    dim3(256), 0, stream, mask, dinv, w2p);
    hipLaunchKernelGGL(k_w2r,  dim3(12),    dim3(256), 0, stream, w2p, dinv, w2sum);
    hipLaunchKernelGGL(k_exp,  dim3(576),   dim3(256), 0, stream, mask, dinv, ATn);
    hipLaunchKernelGGL(k_y1,   dim3(384),   dim3(256), 0, stream, x, W1, y1t);
    hipLaunchKernelGGL(k_prop1, dim3(48, 4), dim3(256), 0, stream, ATn, y1t, b1, h1r);
    hipLaunchKernelGGL(k_v,    dim3(12),    dim3(256), 0, stream, w2sum, h1r, vp);
    hipLaunchKernelGGL(k_head, dim3(1),     dim3(256), 0, stream,
                       vp, W2, b2, l1W, l1b, lng, lnb, l2W, l2b, out);
}

// Round 2
// 227.001 us; speedup vs baseline: 1.2821x; 1.2821x over previous
//
#include <hip/hip_runtime.h>
#include <hip/hip_bf16.h>

// Problem constants
#define NN     3072
#define NWORDS 48          // 3072/64 bit-words per row
#define INCH   128
#define HID    256
#define NHEADS 12
#define PLANE  9437184LL   // 3072*3072

typedef __attribute__((ext_vector_type(8))) short     s16x8;
typedef __attribute__((ext_vector_type(4))) float     f32x4;
typedef __attribute__((ext_vector_type(8))) unsigned short u16x8;

__device__ inline unsigned short bf16_rne(float f) {
    unsigned int u = __float_as_uint(f);
    u += 0x7FFFu + ((u >> 16) & 1u);
    return (unsigned short)(u >> 16);
}

// ---------------------------------------------------------------------------
// K1: stream attn (453 MB) over 64x64 tiles; emit row bitmask (ballot) AND
// bit-transposed mask (LDS chunk assembly). grid 2304 (48 t-tiles x 48 s-tiles).
// wave w handles s = s0+w*16..+16, lane = t offset.
// ---------------------------------------------------------------------------
__global__ __launch_bounds__(256) void k_adj(const float* __restrict__ attn,
                                             const float* __restrict__ agg_w,
                                             const float* __restrict__ agg_b,
                                             unsigned long long* __restrict__ mask,
                                             unsigned long long* __restrict__ maskT) {
    __shared__ unsigned short chunk[4][64];
    const int w = threadIdx.x >> 6, l = threadIdx.x & 63;
    const int t0 = (blockIdx.x % 48) * 64;
    const int s0 = (blockIdx.x / 48) * 64;
    const int t = t0 + l;

    float wc[NHEADS];
#pragma unroll
    for (int c = 0; c < NHEADS; ++c) wc[c] = agg_w[c];
    const float bias = agg_b[0];

    unsigned int colchunk = 0;
#pragma unroll 2
    for (int i = 0; i < 16; ++i) {
        const int s = s0 + w * 16 + i;
        const float* p = attn + (long long)s * NN + t;
        float acc = bias;
#pragma unroll
        for (int c = 0; c < NHEADS; ++c)
            acc = fmaf(wc[c], p[(long long)c * PLANE], acc);
        bool pred = (acc > 0.0f) || (s == t);
        unsigned long long word = __ballot(pred);
        if (l == 0) mask[s * NWORDS + (t0 >> 6)] = word;
        colchunk |= (pred ? 1u : 0u) << i;
    }
    chunk[w][l] = (unsigned short)colchunk;
    __syncthreads();
    if (threadIdx.x < 64) {
        unsigned long long m = (unsigned long long)chunk[0][threadIdx.x]
                             | ((unsigned long long)chunk[1][threadIdx.x] << 16)
                             | ((unsigned long long)chunk[2][threadIdx.x] << 32)
                             | ((unsigned long long)chunk[3][threadIdx.x] << 48);
        maskT[(long long)(t0 + threadIdx.x) * NWORDS + (s0 >> 6)] = m;
    }
}

// ---------------------------------------------------------------------------
// K2: deg[t] = popcount(maskT row t); dinv = rsqrt(deg); dinvb = bf16(dinv).
// grid 12 x 256.
// ---------------------------------------------------------------------------
__global__ __launch_bounds__(256) void k_dinv(const unsigned long long* __restrict__ maskT,
                                              float* __restrict__ dinv,
                                              unsigned short* __restrict__ dinvb) {
    int t = blockIdx.x * 256 + threadIdx.x;
    const unsigned long long* row = maskT + (long long)t * NWORDS;
    int deg = 0;
#pragma unroll
    for (int w = 0; w < NWORDS; ++w) deg += __popcll(row[w]);
    float di = rsqrtf((float)deg);   // deg >= 1 (self loop)
    dinv[t] = di;
    dinvb[t] = bf16_rne(di);
}

// ---------------------------------------------------------------------------
// K3 fused (role-split):
//  blocks [0,768):   w2sum — wave per s-row: w2sum[s] = dinv[s]*sum_t dinv[t]*bit[s][t]
//  blocks [768,1152): y1   — y1t[d][s] = bf16((x@W1)[s][d]) transposed store
// ---------------------------------------------------------------------------
__global__ __launch_bounds__(256) void k_fused(const unsigned long long* __restrict__ mask,
                                               const float* __restrict__ dinv,
                                               const float* __restrict__ x,
                                               const float* __restrict__ W1,
                                               float* __restrict__ w2sum,
                                               unsigned short* __restrict__ y1t) {
    if (blockIdx.x < 768) {
        // --- w2sum: wave per s ---
        const int w = threadIdx.x >> 6, l = threadIdx.x & 63;
        const int s = blockIdx.x * 4 + w;
        unsigned long long myword = (l < NWORDS) ? mask[s * NWORDS + l] : 0ULL;
        float acc = 0.0f;
#pragma unroll 8
        for (int j = 0; j < NWORDS; ++j) {
            unsigned long long wj = __shfl(myword, j);
            float dv = dinv[j * 64 + l];
            acc += ((wj >> l) & 1ULL) ? dv : 0.0f;
        }
#pragma unroll
        for (int o = 1; o < 64; o <<= 1) acc += __shfl_xor(acc, o);
        if (l == 0) w2sum[s] = dinv[s] * acc;
    } else {
        // --- y1: block = 8 s-rows, thread = d ---
        __shared__ float xs[8][INCH];
        int s0 = (blockIdx.x - 768) * 8;
        for (int i = threadIdx.x; i < 8 * INCH; i += 256)
            xs[i >> 7][i & 127] = x[s0 * INCH + i];
        __syncthreads();
        int d = threadIdx.x;
        float acc[8] = {0, 0, 0, 0, 0, 0, 0, 0};
        for (int k = 0; k < INCH; ++k) {
            float w = W1[k * HID + d];
#pragma unroll
            for (int r = 0; r < 8; ++r) acc[r] = fmaf(xs[r][k], w, acc[r]);
        }
        u16x8 v;
#pragma unroll
        for (int r = 0; r < 8; ++r) v[r] = bf16_rne(acc[r]);
        *(u16x8*)(y1t + (long long)d * NN + s0) = v;
    }
}

// ---------------------------------------------------------------------------
// K4: prop1 MFMA GEMM with in-register A expansion from maskT bits.
// partial[z][t][d] = sum_{k in slice z} bit(k,t)*dinv_b[k]*y1[k][d]
// grid (48 t-blocks, 2 d-blocks of 128, 4 k-slices of 768), 256 thr / 4 waves.
// dinv[t] row factor applied later (epilogue of k_vred) — MFMA linear in A.
// ---------------------------------------------------------------------------
__global__ __launch_bounds__(256) void k_prop(const unsigned long long* __restrict__ maskT,
                                              const unsigned short* __restrict__ dinvb,
                                              const unsigned short* __restrict__ y1t,
                                              float* __restrict__ partials) {
    const int w = threadIdx.x >> 6, l = threadIdx.x & 63;
    const int lr = l & 15, lg = l >> 4;
    const int t0 = blockIdx.x * 64 + w * 16;
    const int d0 = blockIdx.y * 128;
    const int z  = blockIdx.z;

    const unsigned long long* mrow = maskT + (long long)(t0 + lr) * NWORDS + z * 12;

    const unsigned short* B[8];
#pragma unroll
    for (int n = 0; n < 8; ++n)
        B[n] = y1t + (long long)(d0 + n * 16 + lr) * NN;

    f32x4 acc[8];
#pragma unroll
    for (int n = 0; n < 8; ++n) acc[n] = (f32x4){0.f, 0.f, 0.f, 0.f};

#pragma unroll 2
    for (int kw = 0; kw < 12; ++kw) {
        unsigned long long word = mrow[kw];
#pragma unroll
        for (int half = 0; half < 2; ++half) {
            const int k0 = z * 768 + kw * 64 + half * 32 + lg * 8;
            unsigned int bits = (unsigned int)((word >> (half * 32 + lg * 8)) & 0xFFULL);
            u16x8 dv = *(const u16x8*)(dinvb + k0);
            s16x8 av;
#pragma unroll
            for (int j = 0; j < 8; ++j)
                av[j] = ((bits >> j) & 1u) ? (short)dv[j] : (short)0;
#pragma unroll
            for (int n = 0; n < 8; ++n) {
                s16x8 bv = *(const s16x8*)(const void*)(B[n] + k0);
                acc[n] = __builtin_amdgcn_mfma_f32_16x16x32_bf16(av, bv, acc[n], 0, 0, 0);
            }
        }
    }

    const int trow = t0 + lg * 4;
#pragma unroll
    for (int n = 0; n < 8; ++n) {
        const int d = d0 + n * 16 + lr;
#pragma unroll
        for (int r = 0; r < 4; ++r)
            partials[((size_t)z * NN + trow + r) * HID + d] = acc[n][r];
    }
}

// ---------------------------------------------------------------------------
// K5: vred — reduce k-slices, apply dinv[t]/bias/relu, fold weighted col-sum:
// vp[b][d] = sum_{t in block} w2sum[t] * relu(dinv[t]*sum_z partial[z][t][d] + b1[d])
// grid 384 (8 t each) x 256.
// ---------------------------------------------------------------------------
__global__ __launch_bounds__(256) void k_vred(const float* __restrict__ partials,
                                              const float* __restrict__ dinv,
                                              const float* __restrict__ b1,
                                              const float* __restrict__ w2sum,
                                              float* __restrict__ vp) {
    const int b = blockIdx.x, d = threadIdx.x;
    const float bb = b1[d];
    float vacc = 0.0f;
#pragma unroll
    for (int i = 0; i < 8; ++i) {
        const int t = b * 8 + i;
        float ssum = partials[((size_t)0 * NN + t) * HID + d]
                   + partials[((size_t)1 * NN + t) * HID + d]
                   + partials[((size_t)2 * NN + t) * HID + d]
                   + partials[((size_t)3 * NN + t) * HID + d];
        float h = fmaxf(fmaf(dinv[t], ssum, bb), 0.0f);
        vacc = fmaf(w2sum[t], h, vacc);
    }
    vp[b * HID + d] = vacc;
}

// ---------------------------------------------------------------------------
// K6: head. g = b2 + (v@W2)/3072 ; z=relu(g@l1W+l1b); LN; out = z@l2W+l2b.
// ---------------------------------------------------------------------------
__global__ __launch_bounds__(256) void k_head(const float* __restrict__ vp,
                                              const float* __restrict__ W2,
                                              const float* __restrict__ b2,
                                              const float* __restrict__ l1W,
                                              const float* __restrict__ l1b,
                                              const float* __restrict__ lng,
                                              const float* __restrict__ lnb,
                                              const float* __restrict__ l2W,
                                              const float* __restrict__ l2b,
                                              float* __restrict__ out) {
    __shared__ float vs[HID], gs[HID], zs[HID], red[4];
    int d = threadIdx.x;
    float v = 0.0f;
    for (int c = 0; c < 384; ++c) v += vp[c * HID + d];
    vs[d] = v;
    __syncthreads();
    float a = 0.0f;
    for (int k = 0; k < HID; ++k) a = fmaf(vs[k], W2[k * HID + d], a);
    gs[d] = b2[d] + a * (1.0f / 3072.0f);
    __syncthreads();
    float z1 = l1b[d];
    for (int k = 0; k < HID; ++k) z1 = fmaf(gs[k], l1W[k * HID + d], z1);
    z1 = fmaxf(z1, 0.0f);
    float sum = z1;
    for (int o = 1; o < 64; o <<= 1) sum += __shfl_xor(sum, o);
    if ((d & 63) == 0) red[d >> 6] = sum;
    __syncthreads();
    float mu = (red[0] + red[1] + red[2] + red[3]) * (1.0f / 256.0f);
    __syncthreads();
    float diff = z1 - mu, sq = diff * diff;
    for (int o = 1; o < 64; o <<= 1) sq += __shfl_xor(sq, o);
    if ((d & 63) == 0) red[d >> 6] = sq;
    __syncthreads();
    float var = (red[0] + red[1] + red[2] + red[3]) * (1.0f / 256.0f);
    float zn = diff * rsqrtf(var + 1e-5f) * lng[d] + lnb[d];
    zs[d] = zn;
    __syncthreads();
    if (d < 32) {
        float o = l2b[d];
        for (int k = 0; k < HID; ++k) o = fmaf(zs[k], l2W[k * 32 + d], o);
        out[d] = o;
    }
}

// ---------------------------------------------------------------------------
extern "C" void kernel_launch(void* const* d_in, const int* in_sizes, int n_in,
                              void* d_out, int out_size, void* d_ws, size_t ws_size,
                              hipStream_t stream) {
    const float* x     = (const float*)d_in[0];
    const float* attn  = (const float*)d_in[1];
    const float* agg_w = (const float*)d_in[4];
    const float* agg_b = (const float*)d_in[5];
    const float* W1    = (const float*)d_in[6];
    const float* b1    = (const float*)d_in[7];
    const float* W2    = (const float*)d_in[8];
    const float* b2    = (const float*)d_in[9];
    const float* l1W   = (const float*)d_in[10];
    const float* l1b   = (const float*)d_in[11];
    const float* lng   = (const float*)d_in[12];
    const float* lnb   = (const float*)d_in[13];
    const float* l2W   = (const float*)d_in[14];
    const float* l2b   = (const float*)d_in[15];
    float* out = (float*)d_out;

    char* ws = (char*)d_ws;
    size_t off = 0;
    auto alloc = [&](size_t bytes) -> void* {
        off = (off + 255) & ~(size_t)255;
        void* p = ws + off;
        off += bytes;
        return p;
    };
    unsigned long long* mask  = (unsigned long long*)alloc((size_t)NN * NWORDS * 8);
    unsigned long long* maskT = (unsigned long long*)alloc((size_t)NN * NWORDS * 8);
    float*          dinv  = (float*)alloc((size_t)NN * 4);
    unsigned short* dinvb = (unsigned short*)alloc((size_t)NN * 2);
    float*          w2sum = (float*)alloc((size_t)NN * 4);
    unsigned short* y1t   = (unsigned short*)alloc((size_t)HID * NN * 2);
    float*          part  = (float*)alloc((size_t)4 * NN * HID * 4);
    float*          vp    = (float*)alloc((size_t)384 * HID * 4);

    hipLaunchKernelGGL(k_adj,   dim3(2304), dim3(256), 0, stream, attn, agg_w, agg_b, mask, maskT);
    hipLaunchKernelGGL(k_dinv,  dim3(12),   dim3(256), 0, stream, maskT, dinv, dinvb);
    hipLaunchKernelGGL(k_fused, dim3(1152), dim3(256), 0, stream, mask, dinv, x, W1, w2sum, y1t);
    hipLaunchKernelGGL(k_prop,  dim3(48, 2, 4), dim3(256), 0, stream, maskT, dinvb, y1t, part);
    hipLaunchKernelGGL(k_vred,  dim3(384),  dim3(256), 0, stream, part, dinv, b1, w2sum, vp);
    hipLaunchKernelGGL(k_head,  dim3(1),    dim3(256), 0, stream,
                       vp, W2, b2, l1W, l1b, lng, lnb, l2W, l2b, out);
}

// Round 3
// 191.652 us; speedup vs baseline: 1.5186x; 1.1844x over previous
//
#include <hip/hip_runtime.h>
#include <hip/hip_bf16.h>

// Problem constants
#define NN     3072
#define NW32   96          // 3072/32 u32-words per maskT row
#define INCH   128
#define HID    256
#define NHEADS 12
#define PLANE  9437184LL   // 3072*3072

typedef __attribute__((ext_vector_type(8))) short     s16x8;
typedef __attribute__((ext_vector_type(4))) float     f32x4;
typedef __attribute__((ext_vector_type(8))) unsigned short u16x8;
typedef __attribute__((ext_vector_type(4))) unsigned int   u32x4;

__device__ inline unsigned short bf16_rne(float f) {
    unsigned int u = __float_as_uint(f);
    u += 0x7FFFu + ((u >> 16) & 1u);
    return (unsigned short)(u >> 16);
}

// ---------------------------------------------------------------------------
// L1: role-split launch.
//  blocks [0,1152):    adj — stream attn (453 MB) in 256t x 32s tiles, float4
//                      loads, emit bit-transposed mask (u32 words).
//  blocks [1152,1536): y1 — y1t[d][s] = bf16((x@W1)[s][d]) transposed store.
// ---------------------------------------------------------------------------
__global__ __launch_bounds__(256) void k_adj_y1(const float* __restrict__ attn,
                                                const float* __restrict__ agg_w,
                                                const float* __restrict__ agg_b,
                                                const float* __restrict__ x,
                                                const float* __restrict__ W1,
                                                unsigned int* __restrict__ maskT32,
                                                unsigned short* __restrict__ y1t) {
    __shared__ unsigned int chunkU[4][64];   // adj: colbits per wave per lane
    __shared__ float xs[8][INCH];            // y1

    if (blockIdx.x < 1152) {
        const int w = threadIdx.x >> 6, l = threadIdx.x & 63;
        const int t0 = (blockIdx.x % 12) * 256;   // 12 consecutive blocks share s-rows
        const int s0 = (blockIdx.x / 12) * 32;
        const int tb = t0 + 4 * l;

        float wc[NHEADS];
#pragma unroll
        for (int c = 0; c < NHEADS; ++c) wc[c] = agg_w[c];
        const float bias = agg_b[0];

        const float* base = attn + (long long)(s0 + 8 * w) * NN + tb;
        unsigned int colb = 0;
#pragma unroll 2
        for (int i = 0; i < 8; ++i) {
            const int s = s0 + 8 * w + i;
            const float* ps = base + (long long)i * NN;
            f32x4 acc = {bias, bias, bias, bias};
#pragma unroll
            for (int c = 0; c < NHEADS; ++c) {
                f32x4 v = *(const f32x4*)(ps + c * PLANE);
                acc[0] = fmaf(wc[c], v[0], acc[0]);
                acc[1] = fmaf(wc[c], v[1], acc[1]);
                acc[2] = fmaf(wc[c], v[2], acc[2]);
                acc[3] = fmaf(wc[c], v[3], acc[3]);
            }
            unsigned int bset = 0;
            bset |= (acc[0] > 0.0f || s == tb + 0) ? (1u << i)        : 0u;
            bset |= (acc[1] > 0.0f || s == tb + 1) ? (1u << (8 + i))  : 0u;
            bset |= (acc[2] > 0.0f || s == tb + 2) ? (1u << (16 + i)) : 0u;
            bset |= (acc[3] > 0.0f || s == tb + 3) ? (1u << (24 + i)) : 0u;
            colb |= bset;
        }
        chunkU[w][l] = colb;
        __syncthreads();
        // thread tl assembles u32 word for t = t0 + tl (32 s-bits of this tile)
        const int l2 = threadIdx.x >> 2, j = threadIdx.x & 3;
        unsigned int word =  ((chunkU[0][l2] >> (8 * j)) & 0xFFu)
                          | (((chunkU[1][l2] >> (8 * j)) & 0xFFu) << 8)
                          | (((chunkU[2][l2] >> (8 * j)) & 0xFFu) << 16)
                          | (((chunkU[3][l2] >> (8 * j)) & 0xFFu) << 24);
        maskT32[(long long)(t0 + threadIdx.x) * NW32 + (s0 >> 5)] = word;
    } else {
        // --- y1: block = 8 s-rows, thread = d ---
        int s0 = (blockIdx.x - 1152) * 8;
        for (int i = threadIdx.x; i < 8 * INCH; i += 256)
            xs[i >> 7][i & 127] = x[s0 * INCH + i];
        __syncthreads();
        int d = threadIdx.x;
        float acc[8] = {0, 0, 0, 0, 0, 0, 0, 0};
        for (int k = 0; k < INCH; ++k) {
            float w = W1[k * HID + d];
#pragma unroll
            for (int r = 0; r < 8; ++r) acc[r] = fmaf(xs[r][k], w, acc[r]);
        }
        u16x8 v;
#pragma unroll
        for (int r = 0; r < 8; ++r) v[r] = bf16_rne(acc[r]);
        *(u16x8*)(y1t + (long long)d * NN + s0) = v;
    }
}

// ---------------------------------------------------------------------------
// L2: deg[t] = popcount(maskT row t); dinv = rsqrt(deg); dinvb = bf16(dinv).
// grid 12 x 256.
// ---------------------------------------------------------------------------
__global__ __launch_bounds__(256) void k_dinv(const unsigned int* __restrict__ maskT32,
                                              float* __restrict__ dinv,
                                              unsigned short* __restrict__ dinvb) {
    int t = blockIdx.x * 256 + threadIdx.x;
    const u32x4* row = (const u32x4*)(maskT32 + (long long)t * NW32);
    int deg = 0;
#pragma unroll
    for (int i = 0; i < 24; ++i) {
        u32x4 v = row[i];
        deg += __popc(v[0]) + __popc(v[1]) + __popc(v[2]) + __popc(v[3]);
    }
    float di = rsqrtf((float)deg);   // deg >= 1 (self loop)
    dinv[t] = di;
    dinvb[t] = bf16_rne(di);
}

// ---------------------------------------------------------------------------
// L3: role-split launch.
//  blocks [0,384):   prop1 MFMA GEMM, in-register A expansion from maskT bits.
//      partial[z][t][d] = sum_{k in slice z} bit(k,t)*dinv_b[k]*y1[k][d]
//      decode: tb = bid%48 (64 t), db = (bid/48)%2 (128 d), z = bid/96 (768 k)
//  blocks [384,960): w2p — column pass: w2p[tc][s] = sum_{t in chunk tc} dinv[t]*bit(s,t)
//      decode: wq = r%48 (u64 word = 64 s), tc = r/48 (256 t)
// ---------------------------------------------------------------------------
__global__ __launch_bounds__(256) void k_prop(const unsigned int* __restrict__ maskT32,
                                              const unsigned short* __restrict__ dinvb,
                                              const unsigned short* __restrict__ y1t,
                                              const float* __restrict__ dinv,
                                              float* __restrict__ partials,
                                              float* __restrict__ w2p) {
    if (blockIdx.x < 384) {
        const int w = threadIdx.x >> 6, l = threadIdx.x & 63;
        const int lr = l & 15, lg = l >> 4;
        const int t0 = (blockIdx.x % 48) * 64 + w * 16;
        const int d0 = ((blockIdx.x / 48) % 2) * 128;
        const int z  = blockIdx.x / 96;

        const unsigned long long* mrow =
            (const unsigned long long*)(maskT32 + (long long)(t0 + lr) * NW32) + z * 12;

        const unsigned short* B[8];
#pragma unroll
        for (int n = 0; n < 8; ++n)
            B[n] = y1t + (long long)(d0 + n * 16 + lr) * NN;

        f32x4 acc[8];
#pragma unroll
        for (int n = 0; n < 8; ++n) acc[n] = (f32x4){0.f, 0.f, 0.f, 0.f};

#pragma unroll 2
        for (int kw = 0; kw < 12; ++kw) {
            unsigned long long word = mrow[kw];
#pragma unroll
            for (int half = 0; half < 2; ++half) {
                const int k0 = z * 768 + kw * 64 + half * 32 + lg * 8;
                unsigned int bits = (unsigned int)((word >> (half * 32 + lg * 8)) & 0xFFULL);
                u16x8 dv = *(const u16x8*)(dinvb + k0);
                s16x8 av;
#pragma unroll
                for (int j = 0; j < 8; ++j)
                    av[j] = ((bits >> j) & 1u) ? (short)dv[j] : (short)0;
#pragma unroll
                for (int n = 0; n < 8; ++n) {
                    s16x8 bv = *(const s16x8*)(const void*)(B[n] + k0);
                    acc[n] = __builtin_amdgcn_mfma_f32_16x16x32_bf16(av, bv, acc[n], 0, 0, 0);
                }
            }
        }

        const int trow = t0 + lg * 4;
#pragma unroll
        for (int n = 0; n < 8; ++n) {
            const int d = d0 + n * 16 + lr;
#pragma unroll
            for (int r = 0; r < 4; ++r)
                partials[((size_t)z * NN + trow + r) * HID + d] = acc[n][r];
        }
    } else {
        // --- w2p column pass ---
        __shared__ float red[4][64];
        const int r = blockIdx.x - 384;
        const int wq = r % 48;           // u64 word index (64 s-columns)
        const int tc = r / 48;           // 256-t chunk
        const int wv = threadIdx.x >> 6, l = threadIdx.x & 63;
        const unsigned long long* mt = (const unsigned long long*)maskT32;
        float acc = 0.0f;
#pragma unroll 4
        for (int it = 0; it < 64; ++it) {
            const int t = tc * 256 + wv * 64 + it;
            unsigned long long word = mt[(long long)t * 48 + wq];  // wave-uniform
            acc += ((word >> l) & 1ULL) ? dinv[t] : 0.0f;
        }
        red[wv][l] = acc;
        __syncthreads();
        if (threadIdx.x < 64)
            w2p[tc * NN + wq * 64 + threadIdx.x] =
                red[0][threadIdx.x] + red[1][threadIdx.x] + red[2][threadIdx.x] + red[3][threadIdx.x];
    }
}

// ---------------------------------------------------------------------------
// L4: vred — reduce k-slices, apply dinv[t]/bias/relu, fold weighted col-sum.
// Also reduces w2p -> w2sum for its 8 t-rows.
// vp[b][d] = sum_{t in block} w2sum[t] * relu(dinv[t]*sum_z partial[z][t][d] + b1[d])
// grid 384 x 256.
// ---------------------------------------------------------------------------
__global__ __launch_bounds__(256) void k_vred(const float* __restrict__ partials,
                                              const float* __restrict__ dinv,
                                              const float* __restrict__ b1,
                                              const float* __restrict__ w2p,
                                              float* __restrict__ vp) {
    __shared__ float w2s[8];
    const int b = blockIdx.x, d = threadIdx.x;
    if (threadIdx.x < 8) {
        const int t = b * 8 + threadIdx.x;
        float a = 0.0f;
#pragma unroll
        for (int tc = 0; tc < 12; ++tc) a += w2p[tc * NN + t];
        w2s[threadIdx.x] = dinv[t] * a;
    }
    __syncthreads();
    const float bb = b1[d];
    float vacc = 0.0f;
#pragma unroll
    for (int i = 0; i < 8; ++i) {
        const int t = b * 8 + i;
        float ssum = partials[((size_t)0 * NN + t) * HID + d]
                   + partials[((size_t)1 * NN + t) * HID + d]
                   + partials[((size_t)2 * NN + t) * HID + d]
                   + partials[((size_t)3 * NN + t) * HID + d];
        float h = fmaxf(fmaf(dinv[t], ssum, bb), 0.0f);
        vacc = fmaf(w2s[i], h, vacc);
    }
    vp[b * HID + d] = vacc;
}

// ---------------------------------------------------------------------------
// L5: head. g = b2 + (v@W2)/3072 ; z=relu(g@l1W+l1b); LN; out = z@l2W+l2b.
// ---------------------------------------------------------------------------
__global__ __launch_bounds__(256) void k_head(const float* __restrict__ vp,
                                              const float* __restrict__ W2,
                                              const float* __restrict__ b2,
                                              const float* __restrict__ l1W,
                                              const float* __restrict__ l1b,
                                              const float* __restrict__ lng,
                                              const float* __restrict__ lnb,
                                              const float* __restrict__ l2W,
                                              const float* __restrict__ l2b,
                                              float* __restrict__ out) {
    __shared__ float vs[HID], gs[HID], zs[HID], red[4];
    int d = threadIdx.x;
    float v = 0.0f;
    for (int c = 0; c < 384; ++c) v += vp[c * HID + d];
    vs[d] = v;
    __syncthreads();
    float a = 0.0f;
    for (int k = 0; k < HID; ++k) a = fmaf(vs[k], W2[k * HID + d], a);
    gs[d] = b2[d] + a * (1.0f / 3072.0f);
    __syncthreads();
    float z1 = l1b[d];
    for (int k = 0; k < HID; ++k) z1 = fmaf(gs[k], l1W[k * HID + d], z1);
    z1 = fmaxf(z1, 0.0f);
    float sum = z1;
    for (int o = 1; o < 64; o <<= 1) sum += __shfl_xor(sum, o);
    if ((d & 63) == 0) red[d >> 6] = sum;
    __syncthreads();
    float mu = (red[0] + red[1] + red[2] + red[3]) * (1.0f / 256.0f);
    __syncthreads();
    float diff = z1 - mu, sq = diff * diff;
    for (int o = 1; o < 64; o <<= 1) sq += __shfl_xor(sq, o);
    if ((d & 63) == 0) red[d >> 6] = sq;
    __syncthreads();
    float var = (red[0] + red[1] + red[2] + red[3]) * (1.0f / 256.0f);
    float zn = diff * rsqrtf(var + 1e-5f) * lng[d] + lnb[d];
    zs[d] = zn;
    __syncthreads();
    if (d < 32) {
        float o = l2b[d];
        for (int k = 0; k < HID; ++k) o = fmaf(zs[k], l2W[k * 32 + d], o);
        out[d] = o;
    }
}

// ---------------------------------------------------------------------------
extern "C" void kernel_launch(void* const* d_in, const int* in_sizes, int n_in,
                              void* d_out, int out_size, void* d_ws, size_t ws_size,
                              hipStream_t stream) {
    const float* x     = (const float*)d_in[0];
    const float* attn  = (const float*)d_in[1];
    const float* agg_w = (const float*)d_in[4];
    const float* agg_b = (const float*)d_in[5];
    const float* W1    = (const float*)d_in[6];
    const float* b1    = (const float*)d_in[7];
    const float* W2    = (const float*)d_in[8];
    const float* b2    = (const float*)d_in[9];
    const float* l1W   = (const float*)d_in[10];
    const float* l1b   = (const float*)d_in[11];
    const float* lng   = (const float*)d_in[12];
    const float* lnb   = (const float*)d_in[13];
    const float* l2W   = (const float*)d_in[14];
    const float* l2b   = (const float*)d_in[15];
    float* out = (float*)d_out;

    char* ws = (char*)d_ws;
    size_t off = 0;
    auto alloc = [&](size_t bytes) -> void* {
        off = (off + 255) & ~(size_t)255;
        void* p = ws + off;
        off += bytes;
        return p;
    };
    unsigned int*   maskT32 = (unsigned int*)alloc((size_t)NN * NW32 * 4);
    float*          dinv  = (float*)alloc((size_t)NN * 4);
    unsigned short* dinvb = (unsigned short*)alloc((size_t)NN * 2);
    float*          w2p   = (float*)alloc((size_t)12 * NN * 4);
    unsigned short* y1t   = (unsigned short*)alloc((size_t)HID * NN * 2);
    float*          part  = (float*)alloc((size_t)4 * NN * HID * 4);
    float*          vp    = (float*)alloc((size_t)384 * HID * 4);

    hipLaunchKernelGGL(k_adj_y1, dim3(1536), dim3(256), 0, stream,
                       attn, agg_w, agg_b, x, W1, maskT32, y1t);
    hipLaunchKernelGGL(k_dinv,   dim3(12),   dim3(256), 0, stream, maskT32, dinv, dinvb);
    hipLaunchKernelGGL(k_prop,   dim3(960),  dim3(256), 0, stream,
                       maskT32, dinvb, y1t, dinv, part, w2p);
    hipLaunchKernelGGL(k_vred,   dim3(384),  dim3(256), 0, stream, part, dinv, b1, w2p, vp);
    hipLaunchKernelGGL(k_head,   dim3(1),    dim3(256), 0, stream,
                       vp, W2, b2, l1W, l1b, lng, lnb, l2W, l2b, out);
}